// Round 10
// baseline (20.587 us; speedup 1.0000x reference)
//
#include <hip/hip_runtime.h>
#include <math.h>

#define NB 6   // GRID_N + K basis functions

struct Params {
    float k3, k6, kh;   // ki0/3, ki0/6, ki0/2
    float cL;           // ki1 * 0.5 * ln2
    float ch;           // ki1 * 0.5
};

__device__ __forceinline__ float fexp2(float x) { return __builtin_amdgcn_exp2f(x); }
__device__ __forceinline__ float flog2(float x) { return __builtin_amdgcn_logf(x); }
__device__ __forceinline__ float frcp(float x)  { return __builtin_amdgcn_rcpf(x); }
__device__ __forceinline__ float frsq(float x)  { return __builtin_amdgcn_rsqf(x); }

// MERGED per-cell cubic table: each edge function phi(x) = sb*silu(x) + sp*spline(x)
// is one cubic per cell (spline part exact; silu part 4-point interpolated,
// value err ~2e-5, deriv err ~2e-4 — inputs provably in-grid for this problem).
// Cell layout: u = 1.5x + 5.5, cells 1..9 real, 0/10/11 zero pads (unreachable).
// A = {a0,a1,a2,a3} value coeffs (f-poly); B = {1.5a1, 3a2, 4.5a3, 0} x-deriv.
__device__ __forceinline__ void phi_vd(float x, const float4* __restrict__ t4,
                                       float& v, float& dv) {
    float u = fmaf(x, 1.5f, 5.5f);
    int   i = (int)u;                // trunc; in-grid u>=1 so floor==trunc
    i = i < 0 ? 0 : (i > 11 ? 11 : i);
    float f = u - (float)i;
    float4 A = t4[2 * i];
    float4 B = t4[2 * i + 1];
    v  = fmaf(fmaf(fmaf(A.w, f, A.z), f, A.y), f, A.x);
    dv = fmaf(fmaf(B.z, f, B.y), f, B.x);
}

__device__ __forceinline__ float phi_d(float x, const float4* __restrict__ t4) {
    float u = fmaf(x, 1.5f, 5.5f);
    int   i = (int)u;
    i = i < 0 ? 0 : (i > 11 ? 11 : i);
    float f = u - (float)i;
    float4 B = t4[2 * i + 1];
    return fmaf(fmaf(B.z, f, B.y), f, B.x);
}

// Analytic gradient, half-coordinate log2-space form (validated r7/r9);
// layer-1 phi tables have b0 folded in; layer-2 uses derivative only.
__device__ __forceinline__ void grad_sample(float s1, float s2, float s3,
        const Params& P, const float4* __restrict__ tb, float g[3]) {
    float q   = s1 - s2;
    float m   = s1 + s2 + 1.0f;
    float b   = s3;
    float h2  = fmaf(q, q, b * b);
    float irr = h2 > 0.0f ? frsq(h2) : 0.0f;   // 1/r (0 at h2<=0, JAX where)
    float r   = h2 * irr;
    float t1  = m - r, t2 = m + r;
    float invDet = frcp(t1 * t2);
    float invt1 = t2 * invDet, invt2 = t1 * invDet;
    float Lt1 = flog2(t1), Lt2 = flog2(t2);
    float x0  = fexp2(fmaf(Lt1, P.k3, -Lt2 * P.k6));
    float x1  = fexp2(fmaf(Lt2, P.k3, -Lt1 * P.k6));
    float x2  = (Lt1 + Lt2) * P.cL;

    float S0, D0, S1v, D1, S2v, D2;
    phi_vd(x0, tb,      S0,  D0);
    phi_vd(x1, tb + 24, S1v, D1);
    phi_vd(x2, tb + 48, S2v, D2);
    float hacc = S0 + S1v + S2v;           // b0 folded into table 0
    float dWdh = phi_d(hacc, tb + 72);

    float P0  = dWdh * D0 * x0;
    float P1  = dWdh * D1 * x1;
    float w2c = dWdh * D2;
    float A = P.kh * P0 * invt1;
    float B = P.kh * P1 * invt2;
    float C = invDet * fmaf(-P.k6, P0 + P1, P.ch * w2c);
    float u0 = (B - A) * irr;
    float w  = fmaf(C, m, 0.5f * (A + B));
    float t  = q * fmaf(0.5f, u0, -C);
    g[0] = 2.0f * (w + t);
    g[1] = 2.0f * (w - t);
    g[2] = b * fmaf(-2.0f, C, u0);
}

__device__ __forceinline__ float silu_ref(float x) {
    return x / (1.0f + expf(-x));
}

__global__ __launch_bounds__(256) void kan_grad(
        const float* __restrict__ strain, float* __restrict__ out, int n,
        const float* __restrict__ c0, const float* __restrict__ sb0,
        const float* __restrict__ sp0, const float* __restrict__ b0,
        const float* __restrict__ c1, const float* __restrict__ sb1,
        const float* __restrict__ sp1, const float* __restrict__ ki0,
        const float* __restrict__ ki1) {
    __shared__ float4 tab4[96];   // 4 tables x 12 cells x {value, deriv}

    const int t = threadIdx.x;

    Params P;
    float k = ki0[0], l = ki1[0];
    P.k3 = k * (1.0f / 3.0f);
    P.k6 = k * (1.0f / 6.0f);
    P.kh = k * 0.5f;
    P.cL = l * 0.34657359f;
    P.ch = l * 0.5f;

    if (t < 48) {
        int tbl = t / 12, cell = t % 12;
        bool real = (cell >= 1 && cell <= 9);
        float a0 = 0.0f, a1 = 0.0f, a2 = 0.0f, a3 = 0.0f;
        if (real) {
            float sb = (tbl < 3) ? sb0[tbl] : sb1[0];
            float sp = (tbl < 3) ? sp0[tbl] : sp1[0];
            const float* cp = (tbl < 3) ? (c0 + tbl * NB) : c1;
            int c = cell - 1;                  // real cell index 0..8
            float cv[4];
#pragma unroll
            for (int kk = 0; kk < 4; ++kk) {
                int j = c + kk - 3;
                cv[kk] = (j >= 0 && j < NB) ? cp[j] : 0.0f;
            }
            const float c16 = 1.0f / 6.0f;
            a0 = (cv[0] + 4.0f * cv[1] + cv[2]) * c16 * sp;
            a1 = (cv[2] - cv[0]) * 0.5f * sp;
            a2 = (cv[0] - 2.0f * cv[1] + cv[2]) * 0.5f * sp;
            a3 = (cv[3] - cv[0] + 3.0f * (cv[1] - cv[2])) * c16 * sp;
            // silu part: 4-point interpolating cubic over this cell, scaled by sb
            float xL = (2.0f * (float)cell - 11.0f) * (1.0f / 3.0f);
            const float h3 = 2.0f / 9.0f;       // cell width / 3
            float y0 = sb * silu_ref(xL);
            float y1 = sb * silu_ref(xL + h3);
            float y2 = sb * silu_ref(xL + 2.0f * h3);
            float y3 = sb * silu_ref(xL + 3.0f * h3);
            a0 += y0;
            a1 += -5.5f * y0 + 9.0f * y1 - 4.5f * y2 + y3;
            a2 += 9.0f * y0 - 22.5f * y1 + 18.0f * y2 - 4.5f * y3;
            a3 += -4.5f * y0 + 13.5f * y1 - 13.5f * y2 + 4.5f * y3;
            if (tbl == 0) a0 += b0[0];          // fold bias into layer-1 table 0
        }
        tab4[2 * t]     = make_float4(a0, a1, a2, a3);
        tab4[2 * t + 1] = make_float4(1.5f * a1, 3.0f * a2, 4.5f * a3, 0.0f);
    }
    __syncthreads();

    // ---- per-thread analytic g0 at s=0: t1=t2=1 -> x0=x1=1, x2=0, irr=0;
    // invt1=invt2=invDet=1 -> G = (A+B) + 2C, g0 = (G, G, 0).
    float S0g, D0g, S1g, D1g, S2g, D2g;
    phi_vd(1.0f, tab4,      S0g, D0g);
    phi_vd(1.0f, tab4 + 24, S1g, D1g);
    phi_vd(0.0f, tab4 + 48, S2g, D2g);
    float hacc0 = S0g + S1g + S2g;
    float dW0 = phi_d(hacc0, tab4 + 72);
    float P0g = dW0 * D0g, P1g = dW0 * D1g, w2g = dW0 * D2g;
    float Cg = fmaf(-P.k6, P0g + P1g, P.ch * w2g);
    const float G = P.kh * (P0g + P1g) + 2.0f * Cg;

    const int ngroups = (n + 3) >> 2;  // 4 samples (= 3 float4) per thread-task
    for (int gi = blockIdx.x * blockDim.x + t; gi < ngroups;
         gi += gridDim.x * blockDim.x) {
        int i0 = gi * 4;
        if (i0 + 4 <= n) {
            const float4* sp4 = reinterpret_cast<const float4*>(strain + (size_t)i0 * 3);
            float4 v0 = sp4[0], v1 = sp4[1], v2 = sp4[2];
            float in[12] = { v0.x, v0.y, v0.z, v0.w,
                             v1.x, v1.y, v1.z, v1.w,
                             v2.x, v2.y, v2.z, v2.w };
            float o[12];
#pragma unroll
            for (int kk = 0; kk < 4; ++kk) {
                float g[3];
                grad_sample(in[3 * kk], in[3 * kk + 1], in[3 * kk + 2], P, tab4, g);
                o[3 * kk]     = g[0] - G;
                o[3 * kk + 1] = g[1] - G;
                o[3 * kk + 2] = g[2];
            }
            float4* op4 = reinterpret_cast<float4*>(out + (size_t)i0 * 3);
            op4[0] = make_float4(o[0], o[1], o[2],  o[3]);
            op4[1] = make_float4(o[4], o[5], o[6],  o[7]);
            op4[2] = make_float4(o[8], o[9], o[10], o[11]);
        } else {
            for (int i = i0; i < n; ++i) {
                float g[3];
                grad_sample(strain[3 * i], strain[3 * i + 1], strain[3 * i + 2], P,
                            tab4, g);
                out[3 * i]     = g[0] - G;
                out[3 * i + 1] = g[1] - G;
                out[3 * i + 2] = g[2];
            }
        }
    }
}

extern "C" void kernel_launch(void* const* d_in, const int* in_sizes, int n_in,
                              void* d_out, int out_size, void* d_ws, size_t ws_size,
                              hipStream_t stream) {
    const float* strain = (const float*)d_in[0];
    const float* c0  = (const float*)d_in[1];
    const float* sb0 = (const float*)d_in[2];
    const float* sp0 = (const float*)d_in[3];
    const float* b0  = (const float*)d_in[4];
    const float* c1  = (const float*)d_in[5];
    const float* sb1 = (const float*)d_in[6];
    const float* sp1 = (const float*)d_in[7];
    // d_in[8] = b1: no effect on gradient
    const float* ki0 = (const float*)d_in[9];
    const float* ki1 = (const float*)d_in[10];

    int n = in_sizes[0] / 3;                 // number of samples
    int ngroups = (n + 3) / 4;
    int block = 256;
    int grid = (ngroups + block - 1) / block;
    if (grid > 8192) grid = 8192;

    kan_grad<<<grid, block, 0, stream>>>(strain, (float*)d_out, n,
                                         c0, sb0, sp0, b0, c1, sb1, sp1, ki0, ki1);
}